// Round 9
// baseline (281.897 us; speedup 1.0000x reference)
//
#include <hip/hip_runtime.h>
#include <hip/hip_bf16.h>

// ---------------- problem constants ----------------
#define N_NODES   50000
#define N_EDGES   800000
#define IN_C      256
#define HID_C     128
#define N_GRAPHS  256
#define N_CLASSES 6
#define BN_EPS    1e-5f

// Activations stored CHANNEL-SLICED: h[slice][node][32] bf16 (slice = ch>>5).
// Slice = N*64B = 3.2 MB < 4 MB per-XCD L2. Agg: slice = bid&3; with bid%8->XCD
// round-robin, slice s lives on XCDs {s, s+4} => gathers are L2-resident
// (r6-verified: FETCH 82.7 -> 25.7 MB). Mapping is a perf heuristic only.

using bf16x8 = __attribute__((ext_vector_type(8))) short;
using f32x4  = __attribute__((ext_vector_type(4))) float;

__device__ __forceinline__ ushort f2bf(float f) {
    union { float f; unsigned u; } v; v.f = f;
    unsigned r = v.u + 0x7fffu + ((v.u >> 16) & 1u);
    return (ushort)(r >> 16);
}
__device__ __forceinline__ float bflo(unsigned u) {
    union { unsigned u; float f; } v; v.u = u << 16; return v.f;
}
__device__ __forceinline__ float bfhi(unsigned u) {
    union { unsigned u; float f; } v; v.u = u & 0xffff0000u; return v.f;
}

// ---------------- count + rank in one atomic pass ----------------
__global__ void k_count_rank(const int* __restrict__ col, int* __restrict__ ecnt,
                             int* __restrict__ rank, int e) {
    int i0 = (blockIdx.x * blockDim.x + threadIdx.x) * 4;
    if (i0 + 3 < e) {
        int4 c = *reinterpret_cast<const int4*>(col + i0);
        int4 r;
        r.x = atomicAdd(&ecnt[c.x], 1);
        r.y = atomicAdd(&ecnt[c.y], 1);
        r.z = atomicAdd(&ecnt[c.z], 1);
        r.w = atomicAdd(&ecnt[c.w], 1);
        *reinterpret_cast<int4*>(rank + i0) = r;
    } else {
        for (int i = i0; i < e; ++i) rank[i] = atomicAdd(&ecnt[col[i]], 1);
    }
}

// scan part A + dinv fused
__global__ void k_scanA(const int* __restrict__ ecnt, int* __restrict__ row_ptr,
                        int* __restrict__ bsum, float* __restrict__ dinv, int n) {
    __shared__ int s[256];
    int t = threadIdx.x;
    int i = blockIdx.x * 256 + t;
    int v = (i < n) ? ecnt[i] : 0;
    if (i < n) dinv[i] = rsqrtf((float)(v + 1));  // +1 self loop
    s[t] = v;
    __syncthreads();
    for (int d = 1; d < 256; d <<= 1) {
        int add = (t >= d) ? s[t - d] : 0;
        __syncthreads();
        s[t] += add;
        __syncthreads();
    }
    if (i < n) row_ptr[i] = s[t];
    if (t == 255) bsum[blockIdx.x] = s[255];
}

// fused scanB+scanC: each block redundantly scans bsum (196 entries) in LDS,
// picks its exclusive offset, converts row_ptr to exclusive.
__global__ void k_scanC(const int* __restrict__ ecnt, int* __restrict__ row_ptr,
                        const int* __restrict__ bsum, int nb, int n, int e) {
    __shared__ int s[256];
    int t = threadIdx.x;
    int v = (t < nb) ? bsum[t] : 0;
    s[t] = v;
    __syncthreads();
    for (int d = 1; d < 256; d <<= 1) {
        int add = (t >= d) ? s[t - d] : 0;
        __syncthreads();
        s[t] += add;
        __syncthreads();
    }
    int off = (blockIdx.x > 0) ? s[blockIdx.x - 1] : 0;
    int i = blockIdx.x * 256 + t;
    if (i < n) row_ptr[i] = row_ptr[i] - ecnt[i] + off;
    if (i == 0) row_ptr[n] = e;
}

// atomic-free fill using precomputed ranks; stores wedge = (src, dinv[src]) 8B
__global__ void k_fill(const int* __restrict__ row, const int* __restrict__ col,
                       const int* __restrict__ row_ptr, const int* __restrict__ rank,
                       const float* __restrict__ dinv, int2* __restrict__ wedge, int e) {
    int i0 = (blockIdx.x * blockDim.x + threadIdx.x) * 4;
    if (i0 + 3 < e) {
        int4 c  = *reinterpret_cast<const int4*>(col + i0);
        int4 r  = *reinterpret_cast<const int4*>(row + i0);
        int4 rk = *reinterpret_cast<const int4*>(rank + i0);
        wedge[row_ptr[c.x] + rk.x] = make_int2(r.x, __float_as_int(dinv[r.x]));
        wedge[row_ptr[c.y] + rk.y] = make_int2(r.y, __float_as_int(dinv[r.y]));
        wedge[row_ptr[c.z] + rk.z] = make_int2(r.z, __float_as_int(dinv[r.z]));
        wedge[row_ptr[c.w] + rk.w] = make_int2(r.w, __float_as_int(dinv[r.w]));
    } else {
        for (int i = i0; i < e; ++i)
            wedge[row_ptr[col[i]] + rank[i]] = make_int2(row[i], __float_as_int(dinv[row[i]]));
    }
}

// ---------------- init + weight prep + BN fold (one launch, runs first) ----------
__global__ void k_prepWF(const float* __restrict__ W0, const float* __restrict__ W1,
                         const float* __restrict__ W2, ushort* __restrict__ Wt0,
                         ushort* __restrict__ Wt1, ushort* __restrict__ Wt2,
                         const float* __restrict__ b0, const float* __restrict__ g0,
                         const float* __restrict__ bt0, const float* __restrict__ m0,
                         const float* __restrict__ v0,
                         const float* __restrict__ b1, const float* __restrict__ g1,
                         const float* __restrict__ bt1, const float* __restrict__ m1,
                         const float* __restrict__ v1,
                         const float* __restrict__ b2, const float* __restrict__ g2,
                         const float* __restrict__ bt2, const float* __restrict__ m2,
                         const float* __restrict__ v2,
                         float* __restrict__ fA, float* __restrict__ fC,
                         int* __restrict__ ecnt, int n) {
    int t = blockIdx.x * blockDim.x + threadIdx.x;
    if (t < n) ecnt[t] = 0;
    const int NW0 = 128 * IN_C, NW1 = 128 * HID_C;
    if (t < NW0) {
        int co = t / IN_C, k = t % IN_C;
        Wt0[t] = f2bf(W0[(size_t)k * 128 + co]);
    } else if (t < NW0 + NW1) {
        int u = t - NW0;
        int co = u / HID_C, k = u % HID_C;
        Wt1[u] = f2bf(W1[(size_t)k * 128 + co]);
    } else if (t < NW0 + 2 * NW1) {
        int u = t - NW0 - NW1;
        int co = u / HID_C, k = u % HID_C;
        Wt2[u] = f2bf(W2[(size_t)k * 128 + co]);
    } else if (t < NW0 + 2 * NW1 + 3 * 128) {
        int u = t - NW0 - 2 * NW1;
        int layer = u >> 7, c = u & 127;
        const float *b_, *g_, *bt_, *m_, *v_;
        if (layer == 0)      { b_ = b0; g_ = g0; bt_ = bt0; m_ = m0; v_ = v0; }
        else if (layer == 1) { b_ = b1; g_ = g1; bt_ = bt1; m_ = m1; v_ = v1; }
        else                 { b_ = b2; g_ = g2; bt_ = bt2; m_ = m2; v_ = v2; }
        float A = g_[c] * rsqrtf(v_[c] + BN_EPS);
        fA[u] = A;
        fC[u] = (b_[c] - m_[c]) * A + bt_[c];
    }
}

// ---------------- MFMA GEMM: C[M,128] = A[M,K] @ W[K,128] ----------------
// A: fp32 row-major (AFP32) or bf16 sliced [k>>5][row][32]. C: bf16 sliced.
template <int K, bool AFP32>
__global__ __launch_bounds__(256) void k_gemmbf(const void* __restrict__ Av,
                                                const ushort* __restrict__ Wt,
                                                ushort* __restrict__ Cbf, int M) {
    extern __shared__ char smem[];  // K*128*2 bytes, layout: [col][k] bf16, 16B-XOR swizzled
    const int tid = threadIdx.x;
    constexpr int CPC = K / 8;          // 16B chunks per col
    constexpr int NCH = 128 * CPC;
    for (int c = tid; c < NCH; c += 256) {
        int col = c / CPC, kg = c % CPC;
        float4 v = *reinterpret_cast<const float4*>(Wt + (size_t)col * K + kg * 8);
        int dst = col * (K * 2) + ((kg * 16) ^ ((col & 7) << 4));
        *reinterpret_cast<float4*>(smem + dst) = v;
    }
    __syncthreads();

    const int wave = tid >> 6, lane = tid & 63;
    const int l15 = lane & 15, lg = lane >> 4;
    const int row = blockIdx.x * 64 + wave * 16 + l15;
    const bool rok = (row < M);

    f32x4 acc[8] = {};

#pragma unroll
    for (int ks = 0; ks < K / 32; ++ks) {
        bf16x8 a;
        if (AFP32) {
            const float* Ap = (const float*)Av + (size_t)row * K + ks * 32 + lg * 8;
            float4 f0, f1;
            if (rok) {
                f0 = *reinterpret_cast<const float4*>(Ap);
                f1 = *reinterpret_cast<const float4*>(Ap + 4);
            } else {
                f0 = make_float4(0, 0, 0, 0); f1 = f0;
            }
            a[0] = (short)f2bf(f0.x); a[1] = (short)f2bf(f0.y);
            a[2] = (short)f2bf(f0.z); a[3] = (short)f2bf(f0.w);
            a[4] = (short)f2bf(f1.x); a[5] = (short)f2bf(f1.y);
            a[6] = (short)f2bf(f1.z); a[7] = (short)f2bf(f1.w);
        } else {
            if (rok) {
                const ushort* Ap = (const ushort*)Av + (size_t)ks * M * 32 + (size_t)row * 32 + lg * 8;
                a = *reinterpret_cast<const bf16x8*>(Ap);
            } else {
#pragma unroll
                for (int j = 0; j < 8; ++j) a[j] = 0;
            }
        }
#pragma unroll
        for (int cf = 0; cf < 8; ++cf) {
            int col = cf * 16 + l15;
            int off = col * (K * 2) + ((ks * 64 + lg * 16) ^ ((col & 7) << 4));
            bf16x8 b = *reinterpret_cast<const bf16x8*>(smem + off);
            acc[cf] = __builtin_amdgcn_mfma_f32_16x16x32_bf16(a, b, acc[cf], 0, 0, 0);
        }
    }

    // C/D layout: col = lane&15, row = (lane>>4)*4 + i   [m89-verified]
#pragma unroll
    for (int cf = 0; cf < 8; ++cf) {
        int sl = cf >> 1;
        int off = (cf & 1) * 16 + l15;
#pragma unroll
        for (int i = 0; i < 4; ++i) {
            int r = blockIdx.x * 64 + wave * 16 + lg * 4 + i;
            if (r < M) Cbf[(size_t)sl * M * 32 + (size_t)r * 32 + off] = f2bf(acc[cf][i]);
        }
    }
}

// ---------------- aggregate + folded BN + ReLU  (sliced -> sliced) ----------------
// grid = 4 slices x ceil(N/16); slice = bid&3 (XCD-resident). Block = 4 waves;
// each 16-lane quarter owns ONE node: lane covers 2 channels of the 64B slice row,
// loops the node's edges alone (no cross-lane merge). wedge[e] is a 16-lane
// broadcast load; 4-edge unroll keeps 4 gather chains in flight per quarter
// (16 per wave). Epilogue: 2 channels, folded BN.
__global__ __launch_bounds__(256) void k_aggbf(const ushort* __restrict__ h,
                                               const int* __restrict__ row_ptr,
                                               const int2* __restrict__ wedge,
                                               const float* __restrict__ dinv,
                                               const float* __restrict__ fA,
                                               const float* __restrict__ fC,
                                               ushort* __restrict__ out, int n) {
    const int slice = blockIdx.x & 3;
    const int nb = blockIdx.x >> 2;
    const int wave = threadIdx.x >> 6, lane = threadIdx.x & 63;
    const int q = lane >> 4, l15 = lane & 15;
    const int vtx = nb * 16 + wave * 4 + q;
    if (vtx >= n) return;
    const ushort* hs = h + (size_t)slice * n * 32;
    const int c0 = l15 * 2;  // within-slice channel pair

    int beg = row_ptr[vtx], end = row_ptr[vtx + 1];
    float a0 = 0.f, a1 = 0.f;
    for (int e = beg; e < end; e += 4) {
        int e1 = e + 1, e2 = e + 2, e3 = e + 3;
        bool k1 = e1 < end, k2 = e2 < end, k3 = e3 < end;
        int2 wd0 = wedge[e];
        int2 wd1 = wedge[k1 ? e1 : e];
        int2 wd2 = wedge[k2 ? e2 : e];
        int2 wd3 = wedge[k3 ? e3 : e];
        float w0 = __int_as_float(wd0.y);
        float w1 = k1 ? __int_as_float(wd1.y) : 0.f;
        float w2 = k2 ? __int_as_float(wd2.y) : 0.f;
        float w3 = k3 ? __int_as_float(wd3.y) : 0.f;
        unsigned u0 = *reinterpret_cast<const unsigned*>(hs + (size_t)wd0.x * 32 + c0);
        unsigned u1 = *reinterpret_cast<const unsigned*>(hs + (size_t)wd1.x * 32 + c0);
        unsigned u2 = *reinterpret_cast<const unsigned*>(hs + (size_t)wd2.x * 32 + c0);
        unsigned u3 = *reinterpret_cast<const unsigned*>(hs + (size_t)wd3.x * 32 + c0);
        a0 = fmaf(bflo(u0), w0, a0); a1 = fmaf(bfhi(u0), w0, a1);
        a0 = fmaf(bflo(u1), w1, a0); a1 = fmaf(bfhi(u1), w1, a1);
        a0 = fmaf(bflo(u2), w2, a0); a1 = fmaf(bfhi(u2), w2, a1);
        a0 = fmaf(bflo(u3), w3, a0); a1 = fmaf(bfhi(u3), w3, a1);
    }

    float dv = dinv[vtx];
    float dvv = dv * dv;
    unsigned us = *reinterpret_cast<const unsigned*>(hs + (size_t)vtx * 32 + c0);
    int c = slice * 32 + c0;
    float2 A = *reinterpret_cast<const float2*>(fA + c);
    float2 C = *reinterpret_cast<const float2*>(fC + c);
    float v0 = fmaf(a0, dv * A.x, fmaf(bflo(us), dvv * A.x, C.x));
    float v1 = fmaf(a1, dv * A.y, fmaf(bfhi(us), dvv * A.y, C.y));
    v0 = fmaxf(v0, 0.f); v1 = fmaxf(v1, 0.f);
    unsigned packed = (unsigned)f2bf(v0) | ((unsigned)f2bf(v1) << 16);
    *reinterpret_cast<unsigned*>(out + (size_t)slice * n * 32 + (size_t)vtx * 32 + c0) = packed;
}

// ---------------- pooling + classifier fused: one block (4 waves) per graph -------
// sliced addressing: lane covers channels lane*2, lane*2+1 -> slice lane>>4.
__global__ __launch_bounds__(256) void k_poolfinal(const ushort* __restrict__ h,
                                                   const int* __restrict__ batch,
                                                   const float* __restrict__ lw,
                                                   const float* __restrict__ lb,
                                                   float* __restrict__ out, int n) {
    __shared__ float psum[4][128];
    __shared__ float pool[128];
    int g = blockIdx.x;
    int tid = threadIdx.x;
    int wave = tid >> 6, lane = tid & 63;
    int lo = 0, hi = n;
    while (lo < hi) { int m = (lo + hi) >> 1; if (batch[m] < g) lo = m + 1; else hi = m; }
    int a = lo;
    lo = 0; hi = n;
    int g1 = g + 1;
    while (lo < hi) { int m = (lo + hi) >> 1; if (batch[m] < g1) lo = m + 1; else hi = m; }
    int b = lo;

    const ushort* hs = h + (size_t)(lane >> 4) * n * 32 + (lane & 15) * 2;
    float a0 = 0.f, a1 = 0.f;
    int i = a + wave;
    for (; i + 12 < b; i += 16) {
        unsigned u0 = *reinterpret_cast<const unsigned*>(hs + (size_t)i * 32);
        unsigned u1 = *reinterpret_cast<const unsigned*>(hs + (size_t)(i + 4) * 32);
        unsigned u2 = *reinterpret_cast<const unsigned*>(hs + (size_t)(i + 8) * 32);
        unsigned u3 = *reinterpret_cast<const unsigned*>(hs + (size_t)(i + 12) * 32);
        a0 += bflo(u0) + bflo(u1) + bflo(u2) + bflo(u3);
        a1 += bfhi(u0) + bfhi(u1) + bfhi(u2) + bfhi(u3);
    }
    for (; i < b; i += 4) {
        unsigned u = *reinterpret_cast<const unsigned*>(hs + (size_t)i * 32);
        a0 += bflo(u); a1 += bfhi(u);
    }
    int c0 = lane * 2;
    psum[wave][c0] = a0;
    psum[wave][c0 + 1] = a1;
    __syncthreads();
    if (tid < 128) pool[tid] = psum[0][tid] + psum[1][tid] + psum[2][tid] + psum[3][tid];
    __syncthreads();
    if (tid < N_CLASSES) {
        float inv = 1.0f / fmaxf((float)(b - a), 1.0f);
        float s = 0.f;
        for (int k = 0; k < 128; ++k) s = fmaf(pool[k], lw[k * N_CLASSES + tid], s);
        out[g * N_CLASSES + tid] = s * inv + lb[tid];
    }
}

// ---------------- launch ----------------
extern "C" void kernel_launch(void* const* d_in, const int* in_sizes, int n_in,
                              void* d_out, int out_size, void* d_ws, size_t ws_size,
                              hipStream_t stream) {
    const float* x      = (const float*)d_in[0];
    const int*   ei     = (const int*)d_in[1];
    const int*   batch  = (const int*)d_in[2];
    const float* W0  = (const float*)d_in[3];
    const float* b0  = (const float*)d_in[4];
    const float* g0  = (const float*)d_in[5];
    const float* bt0 = (const float*)d_in[6];
    const float* m0  = (const float*)d_in[7];
    const float* v0  = (const float*)d_in[8];
    const float* W1  = (const float*)d_in[9];
    const float* b1  = (const float*)d_in[10];
    const float* g1  = (const float*)d_in[11];
    const float* bt1 = (const float*)d_in[12];
    const float* m1  = (const float*)d_in[13];
    const float* v1  = (const float*)d_in[14];
    const float* W2  = (const float*)d_in[15];
    const float* b2  = (const float*)d_in[16];
    const float* g2  = (const float*)d_in[17];
    const float* bt2 = (const float*)d_in[18];
    const float* m2  = (const float*)d_in[19];
    const float* v2  = (const float*)d_in[20];
    const float* lw  = (const float*)d_in[21];
    const float* lb  = (const float*)d_in[22];
    float* out = (float*)d_out;

    const int N = in_sizes[2];          // 50000
    const int E = in_sizes[1] / 2;      // 800000
    const int* row = ei;
    const int* col = ei + E;

    char* ws = (char*)d_ws;
    size_t off = 0;
    auto alloc = [&](size_t bytes) {
        void* p = ws + off;
        off += (bytes + 511) & ~(size_t)511;
        return p;
    };
    ushort* hA     = (ushort*)alloc((size_t)N * 128 * 2);   // bf16 activations (sliced)
    ushort* hB     = (ushort*)alloc((size_t)N * 128 * 2);
    ushort* Wt0    = (ushort*)alloc((size_t)128 * IN_C * 2);
    ushort* Wt1    = (ushort*)alloc((size_t)128 * HID_C * 2);
    ushort* Wt2    = (ushort*)alloc((size_t)128 * HID_C * 2);
    int*   ecnt    = (int*)alloc((size_t)N * 4);
    int*   rank    = (int*)alloc((size_t)E * 4);
    int*   row_ptr = (int*)alloc((size_t)(N + 1) * 4);
    int2*  wedge   = (int2*)alloc((size_t)E * 8);
    float* dinv    = (float*)alloc((size_t)N * 4);
    int*   bsum    = (int*)alloc(256 * 4);
    float* fA      = (float*)alloc(3 * 128 * 4);
    float* fC      = (float*)alloc(3 * 128 * 4);

    const int NB_n  = (N + 255) / 256;        // 196
    const int NB_e4 = (E / 4 + 255) / 256;    // 782

    const int PW = (128 * (IN_C + 2 * HID_C) + 3 * 128 + 255) / 256;  // covers N too
    k_prepWF<<<PW, 256, 0, stream>>>(W0, W1, W2, Wt0, Wt1, Wt2,
                                     b0, g0, bt0, m0, v0,
                                     b1, g1, bt1, m1, v1,
                                     b2, g2, bt2, m2, v2, fA, fC, ecnt, N);
    k_count_rank<<<NB_e4, 256, 0, stream>>>(col, ecnt, rank, E);
    k_scanA<<<NB_n, 256, 0, stream>>>(ecnt, row_ptr, bsum, dinv, N);
    k_scanC<<<NB_n, 256, 0, stream>>>(ecnt, row_ptr, bsum, NB_n, N, E);
    k_fill<<<NB_e4, 256, 0, stream>>>(row, col, row_ptr, rank, dinv, wedge, E);

    const int GB = (N + 63) / 64;             // 782
    const int AB = 4 * ((N + 15) / 16);       // 4 slices x 3125

    // layer 0: x fp32 (K=256) -> hB -> hA
    k_gemmbf<IN_C, true><<<GB, 256, IN_C * 128 * 2, stream>>>(x, Wt0, hB, N);
    k_aggbf<<<AB, 256, 0, stream>>>(hB, row_ptr, wedge, dinv, fA, fC, hA, N);
    // layer 1
    k_gemmbf<HID_C, false><<<GB, 256, HID_C * 128 * 2, stream>>>(hA, Wt1, hB, N);
    k_aggbf<<<AB, 256, 0, stream>>>(hB, row_ptr, wedge, dinv, fA + 128, fC + 128, hA, N);
    // layer 2
    k_gemmbf<HID_C, false><<<GB, 256, HID_C * 128 * 2, stream>>>(hA, Wt2, hB, N);
    k_aggbf<<<AB, 256, 0, stream>>>(hB, row_ptr, wedge, dinv, fA + 256, fC + 256, hA, N);

    // pooling + classifier (one block per graph; batch is sorted)
    k_poolfinal<<<N_GRAPHS, 256, 0, stream>>>(hA, batch, lw, lb, out, N);
}

// Round 10
// 225.337 us; speedup vs baseline: 1.2510x; 1.2510x over previous
//
#include <hip/hip_runtime.h>
#include <hip/hip_bf16.h>

// ---------------- problem constants ----------------
#define N_NODES   50000
#define N_EDGES   800000
#define IN_C      256
#define HID_C     128
#define N_GRAPHS  256
#define N_CLASSES 6
#define BN_EPS    1e-5f

// Layout decision (r6/r9-refuted): h stays UNSLICED [node][128] bf16. XCD channel
// slicing cuts FETCH 82->26-37 MB but multiplies per-edge instruction overhead
// (wedge+addressing amortize over 64B not 256B) and adds divergence/wedge-rereads:
// measured 60 (r6) / 55 (r9) vs 34 us unsliced. Unsliced agg sits at the measured
// random-64B-line HBM ceiling (~2.4 TB/s).

using bf16x8 = __attribute__((ext_vector_type(8))) short;
using f32x4  = __attribute__((ext_vector_type(4))) float;

__device__ __forceinline__ ushort f2bf(float f) {
    union { float f; unsigned u; } v; v.f = f;
    unsigned r = v.u + 0x7fffu + ((v.u >> 16) & 1u);
    return (ushort)(r >> 16);
}
__device__ __forceinline__ float bflo(unsigned u) {
    union { unsigned u; float f; } v; v.u = u << 16; return v.f;
}
__device__ __forceinline__ float bfhi(unsigned u) {
    union { unsigned u; float f; } v; v.u = u & 0xffff0000u; return v.f;
}

// ---------------- count + rank in one atomic pass ----------------
__global__ void k_count_rank(const int* __restrict__ col, int* __restrict__ ecnt,
                             int* __restrict__ rank, int e) {
    int i0 = (blockIdx.x * blockDim.x + threadIdx.x) * 4;
    if (i0 + 3 < e) {
        int4 c = *reinterpret_cast<const int4*>(col + i0);
        int4 r;
        r.x = atomicAdd(&ecnt[c.x], 1);
        r.y = atomicAdd(&ecnt[c.y], 1);
        r.z = atomicAdd(&ecnt[c.z], 1);
        r.w = atomicAdd(&ecnt[c.w], 1);
        *reinterpret_cast<int4*>(rank + i0) = r;
    } else {
        for (int i = i0; i < e; ++i) rank[i] = atomicAdd(&ecnt[col[i]], 1);
    }
}

// scan part A + dinv fused
__global__ void k_scanA(const int* __restrict__ ecnt, int* __restrict__ row_ptr,
                        int* __restrict__ bsum, float* __restrict__ dinv, int n) {
    __shared__ int s[256];
    int t = threadIdx.x;
    int i = blockIdx.x * 256 + t;
    int v = (i < n) ? ecnt[i] : 0;
    if (i < n) dinv[i] = rsqrtf((float)(v + 1));  // +1 self loop
    s[t] = v;
    __syncthreads();
    for (int d = 1; d < 256; d <<= 1) {
        int add = (t >= d) ? s[t - d] : 0;
        __syncthreads();
        s[t] += add;
        __syncthreads();
    }
    if (i < n) row_ptr[i] = s[t];
    if (t == 255) bsum[blockIdx.x] = s[255];
}

// fused scanB+scanC: each block redundantly scans bsum in LDS, applies offset.
__global__ void k_scanC(const int* __restrict__ ecnt, int* __restrict__ row_ptr,
                        const int* __restrict__ bsum, int nb, int n, int e) {
    __shared__ int s[256];
    int t = threadIdx.x;
    int v = (t < nb) ? bsum[t] : 0;
    s[t] = v;
    __syncthreads();
    for (int d = 1; d < 256; d <<= 1) {
        int add = (t >= d) ? s[t - d] : 0;
        __syncthreads();
        s[t] += add;
        __syncthreads();
    }
    int off = (blockIdx.x > 0) ? s[blockIdx.x - 1] : 0;
    int i = blockIdx.x * 256 + t;
    if (i < n) row_ptr[i] = row_ptr[i] - ecnt[i] + off;
    if (i == 0) row_ptr[n] = e;
}

// atomic-free fill using precomputed ranks; stores wedge = (src, dinv[src]) 8B
__global__ void k_fill(const int* __restrict__ row, const int* __restrict__ col,
                       const int* __restrict__ row_ptr, const int* __restrict__ rank,
                       const float* __restrict__ dinv, int2* __restrict__ wedge, int e) {
    int i0 = (blockIdx.x * blockDim.x + threadIdx.x) * 4;
    if (i0 + 3 < e) {
        int4 c  = *reinterpret_cast<const int4*>(col + i0);
        int4 r  = *reinterpret_cast<const int4*>(row + i0);
        int4 rk = *reinterpret_cast<const int4*>(rank + i0);
        wedge[row_ptr[c.x] + rk.x] = make_int2(r.x, __float_as_int(dinv[r.x]));
        wedge[row_ptr[c.y] + rk.y] = make_int2(r.y, __float_as_int(dinv[r.y]));
        wedge[row_ptr[c.z] + rk.z] = make_int2(r.z, __float_as_int(dinv[r.z]));
        wedge[row_ptr[c.w] + rk.w] = make_int2(r.w, __float_as_int(dinv[r.w]));
    } else {
        for (int i = i0; i < e; ++i)
            wedge[row_ptr[col[i]] + rank[i]] = make_int2(row[i], __float_as_int(dinv[row[i]]));
    }
}

// ---------------- init + weight prep + BN fold (one launch, runs first) ----------
__global__ void k_prepWF(const float* __restrict__ W0, const float* __restrict__ W1,
                         const float* __restrict__ W2, ushort* __restrict__ Wt0,
                         ushort* __restrict__ Wt1, ushort* __restrict__ Wt2,
                         const float* __restrict__ b0, const float* __restrict__ g0,
                         const float* __restrict__ bt0, const float* __restrict__ m0,
                         const float* __restrict__ v0,
                         const float* __restrict__ b1, const float* __restrict__ g1,
                         const float* __restrict__ bt1, const float* __restrict__ m1,
                         const float* __restrict__ v1,
                         const float* __restrict__ b2, const float* __restrict__ g2,
                         const float* __restrict__ bt2, const float* __restrict__ m2,
                         const float* __restrict__ v2,
                         float* __restrict__ fA, float* __restrict__ fC,
                         int* __restrict__ ecnt, int n) {
    int t = blockIdx.x * blockDim.x + threadIdx.x;
    if (t < n) ecnt[t] = 0;
    const int NW0 = 128 * IN_C, NW1 = 128 * HID_C;
    if (t < NW0) {
        int co = t / IN_C, k = t % IN_C;
        Wt0[t] = f2bf(W0[(size_t)k * 128 + co]);
    } else if (t < NW0 + NW1) {
        int u = t - NW0;
        int co = u / HID_C, k = u % HID_C;
        Wt1[u] = f2bf(W1[(size_t)k * 128 + co]);
    } else if (t < NW0 + 2 * NW1) {
        int u = t - NW0 - NW1;
        int co = u / HID_C, k = u % HID_C;
        Wt2[u] = f2bf(W2[(size_t)k * 128 + co]);
    } else if (t < NW0 + 2 * NW1 + 3 * 128) {
        int u = t - NW0 - 2 * NW1;
        int layer = u >> 7, c = u & 127;
        const float *b_, *g_, *bt_, *m_, *v_;
        if (layer == 0)      { b_ = b0; g_ = g0; bt_ = bt0; m_ = m0; v_ = v0; }
        else if (layer == 1) { b_ = b1; g_ = g1; bt_ = bt1; m_ = m1; v_ = v1; }
        else                 { b_ = b2; g_ = g2; bt_ = bt2; m_ = m2; v_ = v2; }
        float A = g_[c] * rsqrtf(v_[c] + BN_EPS);
        fA[u] = A;
        fC[u] = (b_[c] - m_[c]) * A + bt_[c];
    }
}

// ---------------- MFMA GEMM: Cbf[M,128] = A[M,K] @ W[K,128]  (bf16 out) ----------
template <int K, bool AFP32>
__global__ __launch_bounds__(256) void k_gemmbf(const void* __restrict__ Av,
                                                const ushort* __restrict__ Wt,
                                                ushort* __restrict__ Cbf, int M) {
    extern __shared__ char smem[];  // K*128*2 bytes, layout: [col][k] bf16, 16B-XOR swizzled
    const int tid = threadIdx.x;
    constexpr int CPC = K / 8;          // 16B chunks per col
    constexpr int NCH = 128 * CPC;
    for (int c = tid; c < NCH; c += 256) {
        int col = c / CPC, kg = c % CPC;
        float4 v = *reinterpret_cast<const float4*>(Wt + (size_t)col * K + kg * 8);
        int dst = col * (K * 2) + ((kg * 16) ^ ((col & 7) << 4));
        *reinterpret_cast<float4*>(smem + dst) = v;
    }
    __syncthreads();

    const int wave = tid >> 6, lane = tid & 63;
    const int l15 = lane & 15, lg = lane >> 4;
    const int row = blockIdx.x * 64 + wave * 16 + l15;
    const bool rok = (row < M);

    f32x4 acc[8] = {};

#pragma unroll
    for (int ks = 0; ks < K / 32; ++ks) {
        bf16x8 a;
        if (AFP32) {
            const float* Ap = (const float*)Av + (size_t)row * K + ks * 32 + lg * 8;
            float4 f0, f1;
            if (rok) {
                f0 = *reinterpret_cast<const float4*>(Ap);
                f1 = *reinterpret_cast<const float4*>(Ap + 4);
            } else {
                f0 = make_float4(0, 0, 0, 0); f1 = f0;
            }
            a[0] = (short)f2bf(f0.x); a[1] = (short)f2bf(f0.y);
            a[2] = (short)f2bf(f0.z); a[3] = (short)f2bf(f0.w);
            a[4] = (short)f2bf(f1.x); a[5] = (short)f2bf(f1.y);
            a[6] = (short)f2bf(f1.z); a[7] = (short)f2bf(f1.w);
        } else {
            if (rok) {
                const ushort* Ap = (const ushort*)Av + (size_t)row * K + ks * 32 + lg * 8;
                a = *reinterpret_cast<const bf16x8*>(Ap);
            } else {
#pragma unroll
                for (int j = 0; j < 8; ++j) a[j] = 0;
            }
        }
#pragma unroll
        for (int cf = 0; cf < 8; ++cf) {
            int col = cf * 16 + l15;
            int off = col * (K * 2) + ((ks * 64 + lg * 16) ^ ((col & 7) << 4));
            bf16x8 b = *reinterpret_cast<const bf16x8*>(smem + off);
            acc[cf] = __builtin_amdgcn_mfma_f32_16x16x32_bf16(a, b, acc[cf], 0, 0, 0);
        }
    }

    // C/D layout: col = lane&15, row = (lane>>4)*4 + i   [m89-verified]
#pragma unroll
    for (int cf = 0; cf < 8; ++cf) {
        int col = cf * 16 + l15;
#pragma unroll
        for (int i = 0; i < 4; ++i) {
            int r = blockIdx.x * 64 + wave * 16 + lg * 4 + i;
            if (r < M) Cbf[(size_t)r * 128 + col] = f2bf(acc[cf][i]);
        }
    }
}

// ---------------- aggregate + folded BN + ReLU  (bf16 h -> bf16 out) ----------------
// 4 waves/block, one node per wave (no intra-wave degree divergence). Quarter q
// walks edges beg+q, +4, ...; lane covers 8 channels (16 lanes x 16B = full 256B
// row per quarter). wedge[e] broadcast-loads; 4 slots/iter = 16 row loads in
// flight per wave; masked with w=0. At the random-64B-line HBM ceiling.
__global__ __launch_bounds__(256) void k_aggbf(const ushort* __restrict__ h,
                                               const int* __restrict__ row_ptr,
                                               const int2* __restrict__ wedge,
                                               const float* __restrict__ dinv,
                                               const float* __restrict__ fA,
                                               const float* __restrict__ fC,
                                               ushort* __restrict__ out, int n) {
    int wave = threadIdx.x >> 6, lane = threadIdx.x & 63;
    int vtx = blockIdx.x * 4 + wave;
    if (vtx >= n) return;
    int q = lane >> 4, l15 = lane & 15;
    int c0 = l15 * 8;  // 8 channels per lane
    int2 rp = *reinterpret_cast<const int2*>(row_ptr + vtx);  // beg, end in one load
    int beg = rp.x, end = rp.y;

    float a0 = 0.f, a1 = 0.f, a2 = 0.f, a3 = 0.f;
    float a4 = 0.f, a5 = 0.f, a6 = 0.f, a7 = 0.f;
    for (int e = beg + q; e < end; e += 16) {
        int eB = e + 4, eC = e + 8, eD = e + 12;
        bool kB = eB < end, kC = eC < end, kD = eD < end;
        int2 wd0 = wedge[e];
        int2 wd1 = wedge[kB ? eB : e];
        int2 wd2 = wedge[kC ? eC : e];
        int2 wd3 = wedge[kD ? eD : e];
        float w0 = __int_as_float(wd0.y);
        float w1 = kB ? __int_as_float(wd1.y) : 0.f;
        float w2 = kC ? __int_as_float(wd2.y) : 0.f;
        float w3 = kD ? __int_as_float(wd3.y) : 0.f;
        uint4 u0 = *reinterpret_cast<const uint4*>(h + (size_t)wd0.x * 128 + c0);
        uint4 u1 = *reinterpret_cast<const uint4*>(h + (size_t)wd1.x * 128 + c0);
        uint4 u2 = *reinterpret_cast<const uint4*>(h + (size_t)wd2.x * 128 + c0);
        uint4 u3 = *reinterpret_cast<const uint4*>(h + (size_t)wd3.x * 128 + c0);
        a0 = fmaf(bflo(u0.x), w0, a0); a1 = fmaf(bfhi(u0.x), w0, a1);
        a2 = fmaf(bflo(u0.y), w0, a2); a3 = fmaf(bfhi(u0.y), w0, a3);
        a4 = fmaf(bflo(u0.z), w0, a4); a5 = fmaf(bfhi(u0.z), w0, a5);
        a6 = fmaf(bflo(u0.w), w0, a6); a7 = fmaf(bfhi(u0.w), w0, a7);
        a0 = fmaf(bflo(u1.x), w1, a0); a1 = fmaf(bfhi(u1.x), w1, a1);
        a2 = fmaf(bflo(u1.y), w1, a2); a3 = fmaf(bfhi(u1.y), w1, a3);
        a4 = fmaf(bflo(u1.z), w1, a4); a5 = fmaf(bfhi(u1.z), w1, a5);
        a6 = fmaf(bflo(u1.w), w1, a6); a7 = fmaf(bfhi(u1.w), w1, a7);
        a0 = fmaf(bflo(u2.x), w2, a0); a1 = fmaf(bfhi(u2.x), w2, a1);
        a2 = fmaf(bflo(u2.y), w2, a2); a3 = fmaf(bfhi(u2.y), w2, a3);
        a4 = fmaf(bflo(u2.z), w2, a4); a5 = fmaf(bfhi(u2.z), w2, a5);
        a6 = fmaf(bflo(u2.w), w2, a6); a7 = fmaf(bfhi(u2.w), w2, a7);
        a0 = fmaf(bflo(u3.x), w3, a0); a1 = fmaf(bfhi(u3.x), w3, a1);
        a2 = fmaf(bflo(u3.y), w3, a2); a3 = fmaf(bfhi(u3.y), w3, a3);
        a4 = fmaf(bflo(u3.z), w3, a4); a5 = fmaf(bfhi(u3.z), w3, a5);
        a6 = fmaf(bflo(u3.w), w3, a6); a7 = fmaf(bfhi(u3.w), w3, a7);
    }

    // merge quarter partials
    a0 += __shfl_xor(a0, 16); a0 += __shfl_xor(a0, 32);
    a1 += __shfl_xor(a1, 16); a1 += __shfl_xor(a1, 32);
    a2 += __shfl_xor(a2, 16); a2 += __shfl_xor(a2, 32);
    a3 += __shfl_xor(a3, 16); a3 += __shfl_xor(a3, 32);
    a4 += __shfl_xor(a4, 16); a4 += __shfl_xor(a4, 32);
    a5 += __shfl_xor(a5, 16); a5 += __shfl_xor(a5, 32);
    a6 += __shfl_xor(a6, 16); a6 += __shfl_xor(a6, 32);
    a7 += __shfl_xor(a7, 16); a7 += __shfl_xor(a7, 32);

    if (q == 0) {
        float dv = dinv[vtx];
        float dvv = dv * dv;
        uint4 us = *reinterpret_cast<const uint4*>(h + (size_t)vtx * 128 + c0);
        float4 A0 = *reinterpret_cast<const float4*>(fA + c0);
        float4 A1 = *reinterpret_cast<const float4*>(fA + c0 + 4);
        float4 C0 = *reinterpret_cast<const float4*>(fC + c0);
        float4 C1 = *reinterpret_cast<const float4*>(fC + c0 + 4);
        float v0 = fmaf(a0, dv * A0.x, fmaf(bflo(us.x), dvv * A0.x, C0.x));
        float v1 = fmaf(a1, dv * A0.y, fmaf(bfhi(us.x), dvv * A0.y, C0.y));
        float v2 = fmaf(a2, dv * A0.z, fmaf(bflo(us.y), dvv * A0.z, C0.z));
        float v3 = fmaf(a3, dv * A0.w, fmaf(bfhi(us.y), dvv * A0.w, C0.w));
        float v4 = fmaf(a4, dv * A1.x, fmaf(bflo(us.z), dvv * A1.x, C1.x));
        float v5 = fmaf(a5, dv * A1.y, fmaf(bfhi(us.z), dvv * A1.y, C1.y));
        float v6 = fmaf(a6, dv * A1.z, fmaf(bflo(us.w), dvv * A1.z, C1.z));
        float v7 = fmaf(a7, dv * A1.w, fmaf(bfhi(us.w), dvv * A1.w, C1.w));
        v0 = fmaxf(v0, 0.f); v1 = fmaxf(v1, 0.f); v2 = fmaxf(v2, 0.f); v3 = fmaxf(v3, 0.f);
        v4 = fmaxf(v4, 0.f); v5 = fmaxf(v5, 0.f); v6 = fmaxf(v6, 0.f); v7 = fmaxf(v7, 0.f);
        uint4 packed;
        packed.x = (unsigned)f2bf(v0) | ((unsigned)f2bf(v1) << 16);
        packed.y = (unsigned)f2bf(v2) | ((unsigned)f2bf(v3) << 16);
        packed.z = (unsigned)f2bf(v4) | ((unsigned)f2bf(v5) << 16);
        packed.w = (unsigned)f2bf(v6) | ((unsigned)f2bf(v7) << 16);
        *reinterpret_cast<uint4*>(out + (size_t)vtx * 128 + c0) = packed;
    }
}

// ---------------- pooling + classifier fused: one block (4 waves) per graph -------
__global__ __launch_bounds__(256) void k_poolfinal(const ushort* __restrict__ h,
                                                   const int* __restrict__ batch,
                                                   const float* __restrict__ lw,
                                                   const float* __restrict__ lb,
                                                   float* __restrict__ out, int n) {
    __shared__ float psum[4][128];
    __shared__ float pool[128];
    int g = blockIdx.x;
    int tid = threadIdx.x;
    int wave = tid >> 6, lane = tid & 63;
    int lo = 0, hi = n;
    while (lo < hi) { int m = (lo + hi) >> 1; if (batch[m] < g) lo = m + 1; else hi = m; }
    int a = lo;
    lo = 0; hi = n;
    int g1 = g + 1;
    while (lo < hi) { int m = (lo + hi) >> 1; if (batch[m] < g1) lo = m + 1; else hi = m; }
    int b = lo;

    int c0 = lane * 2;
    float a0 = 0.f, a1 = 0.f;
    int i = a + wave;
    for (; i + 12 < b; i += 16) {
        unsigned u0 = *reinterpret_cast<const unsigned*>(h + (size_t)i * 128 + c0);
        unsigned u1 = *reinterpret_cast<const unsigned*>(h + (size_t)(i + 4) * 128 + c0);
        unsigned u2 = *reinterpret_cast<const unsigned*>(h + (size_t)(i + 8) * 128 + c0);
        unsigned u3 = *reinterpret_cast<const unsigned*>(h + (size_t)(i + 12) * 128 + c0);
        a0 += bflo(u0) + bflo(u1) + bflo(u2) + bflo(u3);
        a1 += bfhi(u0) + bfhi(u1) + bfhi(u2) + bfhi(u3);
    }
    for (; i < b; i += 4) {
        unsigned u = *reinterpret_cast<const unsigned*>(h + (size_t)i * 128 + c0);
        a0 += bflo(u); a1 += bfhi(u);
    }
    psum[wave][c0] = a0;
    psum[wave][c0 + 1] = a1;
    __syncthreads();
    if (tid < 128) pool[tid] = psum[0][tid] + psum[1][tid] + psum[2][tid] + psum[3][tid];
    __syncthreads();
    if (tid < N_CLASSES) {
        float inv = 1.0f / fmaxf((float)(b - a), 1.0f);
        float s = 0.f;
        for (int k = 0; k < 128; ++k) s = fmaf(pool[k], lw[k * N_CLASSES + tid], s);
        out[g * N_CLASSES + tid] = s * inv + lb[tid];
    }
}

// ---------------- launch ----------------
extern "C" void kernel_launch(void* const* d_in, const int* in_sizes, int n_in,
                              void* d_out, int out_size, void* d_ws, size_t ws_size,
                              hipStream_t stream) {
    const float* x      = (const float*)d_in[0];
    const int*   ei     = (const int*)d_in[1];
    const int*   batch  = (const int*)d_in[2];
    const float* W0  = (const float*)d_in[3];
    const float* b0  = (const float*)d_in[4];
    const float* g0  = (const float*)d_in[5];
    const float* bt0 = (const float*)d_in[6];
    const float* m0  = (const float*)d_in[7];
    const float* v0  = (const float*)d_in[8];
    const float* W1  = (const float*)d_in[9];
    const float* b1  = (const float*)d_in[10];
    const float* g1  = (const float*)d_in[11];
    const float* bt1 = (const float*)d_in[12];
    const float* m1  = (const float*)d_in[13];
    const float* v1  = (const float*)d_in[14];
    const float* W2  = (const float*)d_in[15];
    const float* b2  = (const float*)d_in[16];
    const float* g2  = (const float*)d_in[17];
    const float* bt2 = (const float*)d_in[18];
    const float* m2  = (const float*)d_in[19];
    const float* v2  = (const float*)d_in[20];
    const float* lw  = (const float*)d_in[21];
    const float* lb  = (const float*)d_in[22];
    float* out = (float*)d_out;

    const int N = in_sizes[2];          // 50000
    const int E = in_sizes[1] / 2;      // 800000
    const int* row = ei;
    const int* col = ei + E;

    char* ws = (char*)d_ws;
    size_t off = 0;
    auto alloc = [&](size_t bytes) {
        void* p = ws + off;
        off += (bytes + 511) & ~(size_t)511;
        return p;
    };
    ushort* hA     = (ushort*)alloc((size_t)N * 128 * 2);   // bf16 activations
    ushort* hB     = (ushort*)alloc((size_t)N * 128 * 2);
    ushort* Wt0    = (ushort*)alloc((size_t)128 * IN_C * 2);
    ushort* Wt1    = (ushort*)alloc((size_t)128 * HID_C * 2);
    ushort* Wt2    = (ushort*)alloc((size_t)128 * HID_C * 2);
    int*   ecnt    = (int*)alloc((size_t)N * 4);
    int*   rank    = (int*)alloc((size_t)E * 4);
    int*   row_ptr = (int*)alloc((size_t)(N + 1) * 4);
    int2*  wedge   = (int2*)alloc((size_t)E * 8);
    float* dinv    = (float*)alloc((size_t)N * 4);
    int*   bsum    = (int*)alloc(256 * 4);
    float* fA      = (float*)alloc(3 * 128 * 4);
    float* fC      = (float*)alloc(3 * 128 * 4);

    const int NB_n  = (N + 255) / 256;        // 196
    const int NB_e4 = (E / 4 + 255) / 256;    // 782

    const int PW = (128 * (IN_C + 2 * HID_C) + 3 * 128 + 255) / 256;  // covers N too
    k_prepWF<<<PW, 256, 0, stream>>>(W0, W1, W2, Wt0, Wt1, Wt2,
                                     b0, g0, bt0, m0, v0,
                                     b1, g1, bt1, m1, v1,
                                     b2, g2, bt2, m2, v2, fA, fC, ecnt, N);
    k_count_rank<<<NB_e4, 256, 0, stream>>>(col, ecnt, rank, E);
    k_scanA<<<NB_n, 256, 0, stream>>>(ecnt, row_ptr, bsum, dinv, N);
    k_scanC<<<NB_n, 256, 0, stream>>>(ecnt, row_ptr, bsum, NB_n, N, E);
    k_fill<<<NB_e4, 256, 0, stream>>>(row, col, row_ptr, rank, dinv, wedge, E);

    const int GB = (N + 63) / 64;       // 782
    const int AB = (N + 3) / 4;         // 12500

    // layer 0: x fp32 (K=256) -> hB -> hA
    k_gemmbf<IN_C, true><<<GB, 256, IN_C * 128 * 2, stream>>>(x, Wt0, hB, N);
    k_aggbf<<<AB, 256, 0, stream>>>(hB, row_ptr, wedge, dinv, fA, fC, hA, N);
    // layer 1
    k_gemmbf<HID_C, false><<<GB, 256, HID_C * 128 * 2, stream>>>(hA, Wt1, hB, N);
    k_aggbf<<<AB, 256, 0, stream>>>(hB, row_ptr, wedge, dinv, fA + 128, fC + 128, hA, N);
    // layer 2
    k_gemmbf<HID_C, false><<<GB, 256, HID_C * 128 * 2, stream>>>(hA, Wt2, hB, N);
    k_aggbf<<<AB, 256, 0, stream>>>(hB, row_ptr, wedge, dinv, fA + 256, fC + 256, hA, N);

    // pooling + classifier (one block per graph; batch is sorted)
    k_poolfinal<<<N_GRAPHS, 256, 0, stream>>>(hA, batch, lw, lb, out, N);
}

// Round 11
// 209.929 us; speedup vs baseline: 1.3428x; 1.0734x over previous
//
#include <hip/hip_runtime.h>
#include <hip/hip_bf16.h>

// ---------------- problem constants ----------------
#define N_NODES   50000
#define N_EDGES   800000
#define IN_C      256
#define HID_C     128
#define N_GRAPHS  256
#define N_CLASSES 6
#define BN_EPS    1e-5f

// Layout decision (r6/r9-refuted): h stays UNSLICED [node][128] bf16; unsliced agg
// sits at the measured random-line HBM/L3 ceiling (~2.4 TB/s).
// r10 finding: count_rank is atomic-transaction bound (28MB atomic write-through,
// VALU 0.2%) -> hidden inside gemm0 as a 5th "producer" wave (this round).

using bf16x8 = __attribute__((ext_vector_type(8))) short;
using f32x4  = __attribute__((ext_vector_type(4))) float;

__device__ __forceinline__ ushort f2bf(float f) {
    union { float f; unsigned u; } v; v.f = f;
    unsigned r = v.u + 0x7fffu + ((v.u >> 16) & 1u);
    return (ushort)(r >> 16);
}
__device__ __forceinline__ float bflo(unsigned u) {
    union { unsigned u; float f; } v; v.u = u << 16; return v.f;
}
__device__ __forceinline__ float bfhi(unsigned u) {
    union { unsigned u; float f; } v; v.u = u & 0xffff0000u; return v.f;
}

// ---------------- scan part A + dinv fused ----------------
__global__ void k_scanA(const int* __restrict__ ecnt, int* __restrict__ row_ptr,
                        int* __restrict__ bsum, float* __restrict__ dinv, int n) {
    __shared__ int s[256];
    int t = threadIdx.x;
    int i = blockIdx.x * 256 + t;
    int v = (i < n) ? ecnt[i] : 0;
    if (i < n) dinv[i] = rsqrtf((float)(v + 1));  // +1 self loop
    s[t] = v;
    __syncthreads();
    for (int d = 1; d < 256; d <<= 1) {
        int add = (t >= d) ? s[t - d] : 0;
        __syncthreads();
        s[t] += add;
        __syncthreads();
    }
    if (i < n) row_ptr[i] = s[t];
    if (t == 255) bsum[blockIdx.x] = s[255];
}

// fused scanB+scanC: each block redundantly scans bsum in LDS, applies offset.
__global__ void k_scanC(const int* __restrict__ ecnt, int* __restrict__ row_ptr,
                        const int* __restrict__ bsum, int nb, int n, int e) {
    __shared__ int s[256];
    int t = threadIdx.x;
    int v = (t < nb) ? bsum[t] : 0;
    s[t] = v;
    __syncthreads();
    for (int d = 1; d < 256; d <<= 1) {
        int add = (t >= d) ? s[t - d] : 0;
        __syncthreads();
        s[t] += add;
        __syncthreads();
    }
    int off = (blockIdx.x > 0) ? s[blockIdx.x - 1] : 0;
    int i = blockIdx.x * 256 + t;
    if (i < n) row_ptr[i] = row_ptr[i] - ecnt[i] + off;
    if (i == 0) row_ptr[n] = e;
}

// atomic-free fill using precomputed ranks; stores wedge = (src, dinv[src]) 8B
__global__ void k_fill(const int* __restrict__ row, const int* __restrict__ col,
                       const int* __restrict__ row_ptr, const int* __restrict__ rank,
                       const float* __restrict__ dinv, int2* __restrict__ wedge, int e) {
    int i0 = (blockIdx.x * blockDim.x + threadIdx.x) * 4;
    if (i0 + 3 < e) {
        int4 c  = *reinterpret_cast<const int4*>(col + i0);
        int4 r  = *reinterpret_cast<const int4*>(row + i0);
        int4 rk = *reinterpret_cast<const int4*>(rank + i0);
        wedge[row_ptr[c.x] + rk.x] = make_int2(r.x, __float_as_int(dinv[r.x]));
        wedge[row_ptr[c.y] + rk.y] = make_int2(r.y, __float_as_int(dinv[r.y]));
        wedge[row_ptr[c.z] + rk.z] = make_int2(r.z, __float_as_int(dinv[r.z]));
        wedge[row_ptr[c.w] + rk.w] = make_int2(r.w, __float_as_int(dinv[r.w]));
    } else {
        for (int i = i0; i < e; ++i)
            wedge[row_ptr[col[i]] + rank[i]] = make_int2(row[i], __float_as_int(dinv[row[i]]));
    }
}

// ---------------- init + weight prep + BN fold (one launch, runs first) ----------
__global__ void k_prepWF(const float* __restrict__ W0, const float* __restrict__ W1,
                         const float* __restrict__ W2, ushort* __restrict__ Wt0,
                         ushort* __restrict__ Wt1, ushort* __restrict__ Wt2,
                         const float* __restrict__ b0, const float* __restrict__ g0,
                         const float* __restrict__ bt0, const float* __restrict__ m0,
                         const float* __restrict__ v0,
                         const float* __restrict__ b1, const float* __restrict__ g1,
                         const float* __restrict__ bt1, const float* __restrict__ m1,
                         const float* __restrict__ v1,
                         const float* __restrict__ b2, const float* __restrict__ g2,
                         const float* __restrict__ bt2, const float* __restrict__ m2,
                         const float* __restrict__ v2,
                         float* __restrict__ fA, float* __restrict__ fC,
                         int* __restrict__ ecnt, int n) {
    int t = blockIdx.x * blockDim.x + threadIdx.x;
    if (t < n) ecnt[t] = 0;
    const int NW0 = 128 * IN_C, NW1 = 128 * HID_C;
    if (t < NW0) {
        int co = t / IN_C, k = t % IN_C;
        Wt0[t] = f2bf(W0[(size_t)k * 128 + co]);
    } else if (t < NW0 + NW1) {
        int u = t - NW0;
        int co = u / HID_C, k = u % HID_C;
        Wt1[u] = f2bf(W1[(size_t)k * 128 + co]);
    } else if (t < NW0 + 2 * NW1) {
        int u = t - NW0 - NW1;
        int co = u / HID_C, k = u % HID_C;
        Wt2[u] = f2bf(W2[(size_t)k * 128 + co]);
    } else if (t < NW0 + 2 * NW1 + 3 * 128) {
        int u = t - NW0 - 2 * NW1;
        int layer = u >> 7, c = u & 127;
        const float *b_, *g_, *bt_, *m_, *v_;
        if (layer == 0)      { b_ = b0; g_ = g0; bt_ = bt0; m_ = m0; v_ = v0; }
        else if (layer == 1) { b_ = b1; g_ = g1; bt_ = bt1; m_ = m1; v_ = v1; }
        else                 { b_ = b2; g_ = g2; bt_ = bt2; m_ = m2; v_ = v2; }
        float A = g_[c] * rsqrtf(v_[c] + BN_EPS);
        fA[u] = A;
        fC[u] = (b_[c] - m_[c]) * A + bt_[c];
    }
}

// ---------------- FUSED gemm0 (fp32 A, K=256) + count_rank --------------------
// 5 waves: waves 0-3 compute C = x @ W0 (identical to k_gemmbf<256,true>);
// wave 4 processes this block's 1024-edge chunk of count+rank (atomic-latency
// work hides under the MFMA/LDS work of waves 0-3). All 5 waves co-stage W
// to LDS and cross one uniform barrier.
__global__ __launch_bounds__(320) void k_gemm0_count(const float* __restrict__ Av,
                                                     const ushort* __restrict__ Wt,
                                                     ushort* __restrict__ Cbf, int M,
                                                     const int* __restrict__ col,
                                                     int* __restrict__ ecnt,
                                                     int* __restrict__ rank,
                                                     int E, int jiters) {
    constexpr int K = IN_C;
    extern __shared__ char smem[];  // K*128*2 = 64KB, [col][k] bf16, 16B-XOR swizzled
    const int tid = threadIdx.x;
    constexpr int CPC = K / 8;
    constexpr int NCH = 128 * CPC;
    for (int c = tid; c < NCH; c += 320) {
        int col_ = c / CPC, kg = c % CPC;
        float4 v = *reinterpret_cast<const float4*>(Wt + (size_t)col_ * K + kg * 8);
        int dst = col_ * (K * 2) + ((kg * 16) ^ ((col_ & 7) << 4));
        *reinterpret_cast<float4*>(smem + dst) = v;
    }
    __syncthreads();

    if (tid >= 256) {
        // ---- wave 4: count + rank chunk ----
        int lane = tid - 256;
        int base = blockIdx.x * (jiters * 256);
        for (int j = 0; j < jiters; ++j) {
            int i0 = base + (j * 64 + lane) * 4;
            if (i0 + 3 < E) {
                int4 c4 = *reinterpret_cast<const int4*>(col + i0);
                int4 r4;
                r4.x = atomicAdd(&ecnt[c4.x], 1);
                r4.y = atomicAdd(&ecnt[c4.y], 1);
                r4.z = atomicAdd(&ecnt[c4.z], 1);
                r4.w = atomicAdd(&ecnt[c4.w], 1);
                *reinterpret_cast<int4*>(rank + i0) = r4;
            } else {
                for (int i = i0; i < E; ++i) rank[i] = atomicAdd(&ecnt[col[i]], 1);
            }
        }
        return;
    }

    // ---- waves 0-3: gemm ----
    const int wave = tid >> 6, lane = tid & 63;
    const int l15 = lane & 15, lg = lane >> 4;
    const int row = blockIdx.x * 64 + wave * 16 + l15;
    const bool rok = (row < M);

    f32x4 acc[8] = {};

#pragma unroll
    for (int ks = 0; ks < K / 32; ++ks) {
        bf16x8 a;
        const float* Ap = Av + (size_t)row * K + ks * 32 + lg * 8;
        float4 f0, f1;
        if (rok) {
            f0 = *reinterpret_cast<const float4*>(Ap);
            f1 = *reinterpret_cast<const float4*>(Ap + 4);
        } else {
            f0 = make_float4(0, 0, 0, 0); f1 = f0;
        }
        a[0] = (short)f2bf(f0.x); a[1] = (short)f2bf(f0.y);
        a[2] = (short)f2bf(f0.z); a[3] = (short)f2bf(f0.w);
        a[4] = (short)f2bf(f1.x); a[5] = (short)f2bf(f1.y);
        a[6] = (short)f2bf(f1.z); a[7] = (short)f2bf(f1.w);
#pragma unroll
        for (int cf = 0; cf < 8; ++cf) {
            int c = cf * 16 + l15;
            int off = c * (K * 2) + ((ks * 64 + lg * 16) ^ ((c & 7) << 4));
            bf16x8 b = *reinterpret_cast<const bf16x8*>(smem + off);
            acc[cf] = __builtin_amdgcn_mfma_f32_16x16x32_bf16(a, b, acc[cf], 0, 0, 0);
        }
    }

    // C/D layout: col = lane&15, row = (lane>>4)*4 + i   [m89-verified]
#pragma unroll
    for (int cf = 0; cf < 8; ++cf) {
        int c = cf * 16 + l15;
#pragma unroll
        for (int i = 0; i < 4; ++i) {
            int r = blockIdx.x * 64 + wave * 16 + lg * 4 + i;
            if (r < M) Cbf[(size_t)r * 128 + c] = f2bf(acc[cf][i]);
        }
    }
}

// ---------------- MFMA GEMM (bf16 A, K=128): layers 1,2 ----------
template <int K>
__global__ __launch_bounds__(256) void k_gemmbf(const ushort* __restrict__ Av,
                                                const ushort* __restrict__ Wt,
                                                ushort* __restrict__ Cbf, int M) {
    extern __shared__ char smem[];  // K*128*2 bytes, [col][k] bf16, 16B-XOR swizzled
    const int tid = threadIdx.x;
    constexpr int CPC = K / 8;
    constexpr int NCH = 128 * CPC;
    for (int c = tid; c < NCH; c += 256) {
        int col = c / CPC, kg = c % CPC;
        float4 v = *reinterpret_cast<const float4*>(Wt + (size_t)col * K + kg * 8);
        int dst = col * (K * 2) + ((kg * 16) ^ ((col & 7) << 4));
        *reinterpret_cast<float4*>(smem + dst) = v;
    }
    __syncthreads();

    const int wave = tid >> 6, lane = tid & 63;
    const int l15 = lane & 15, lg = lane >> 4;
    const int row = blockIdx.x * 64 + wave * 16 + l15;
    const bool rok = (row < M);

    f32x4 acc[8] = {};

#pragma unroll
    for (int ks = 0; ks < K / 32; ++ks) {
        bf16x8 a;
        if (rok) {
            const ushort* Ap = Av + (size_t)row * K + ks * 32 + lg * 8;
            a = *reinterpret_cast<const bf16x8*>(Ap);
        } else {
#pragma unroll
            for (int j = 0; j < 8; ++j) a[j] = 0;
        }
#pragma unroll
        for (int cf = 0; cf < 8; ++cf) {
            int col = cf * 16 + l15;
            int off = col * (K * 2) + ((ks * 64 + lg * 16) ^ ((col & 7) << 4));
            bf16x8 b = *reinterpret_cast<const bf16x8*>(smem + off);
            acc[cf] = __builtin_amdgcn_mfma_f32_16x16x32_bf16(a, b, acc[cf], 0, 0, 0);
        }
    }

#pragma unroll
    for (int cf = 0; cf < 8; ++cf) {
        int col = cf * 16 + l15;
#pragma unroll
        for (int i = 0; i < 4; ++i) {
            int r = blockIdx.x * 64 + wave * 16 + lg * 4 + i;
            if (r < M) Cbf[(size_t)r * 128 + col] = f2bf(acc[cf][i]);
        }
    }
}

// ---------------- aggregate + folded BN + ReLU  (bf16 h -> bf16 out) ----------------
// 4 waves/block, one node per wave. Quarter q walks edges beg+q, +4, ...; lane
// covers 8 channels (16 lanes x 16B = full 256B row per quarter). wedge[e]
// broadcast-loads; 4 slots/iter = 16 row loads in flight; masked with w=0.
// At the measured random-line fill ceiling (~2.4 TB/s effective).
__global__ __launch_bounds__(256) void k_aggbf(const ushort* __restrict__ h,
                                               const int* __restrict__ row_ptr,
                                               const int2* __restrict__ wedge,
                                               const float* __restrict__ dinv,
                                               const float* __restrict__ fA,
                                               const float* __restrict__ fC,
                                               ushort* __restrict__ out, int n) {
    int wave = threadIdx.x >> 6, lane = threadIdx.x & 63;
    int vtx = blockIdx.x * 4 + wave;
    if (vtx >= n) return;
    int q = lane >> 4, l15 = lane & 15;
    int c0 = l15 * 8;
    int2 rp = *reinterpret_cast<const int2*>(row_ptr + vtx);
    int beg = rp.x, end = rp.y;

    float a0 = 0.f, a1 = 0.f, a2 = 0.f, a3 = 0.f;
    float a4 = 0.f, a5 = 0.f, a6 = 0.f, a7 = 0.f;
    for (int e = beg + q; e < end; e += 16) {
        int eB = e + 4, eC = e + 8, eD = e + 12;
        bool kB = eB < end, kC = eC < end, kD = eD < end;
        int2 wd0 = wedge[e];
        int2 wd1 = wedge[kB ? eB : e];
        int2 wd2 = wedge[kC ? eC : e];
        int2 wd3 = wedge[kD ? eD : e];
        float w0 = __int_as_float(wd0.y);
        float w1 = kB ? __int_as_float(wd1.y) : 0.f;
        float w2 = kC ? __int_as_float(wd2.y) : 0.f;
        float w3 = kD ? __int_as_float(wd3.y) : 0.f;
        uint4 u0 = *reinterpret_cast<const uint4*>(h + (size_t)wd0.x * 128 + c0);
        uint4 u1 = *reinterpret_cast<const uint4*>(h + (size_t)wd1.x * 128 + c0);
        uint4 u2 = *reinterpret_cast<const uint4*>(h + (size_t)wd2.x * 128 + c0);
        uint4 u3 = *reinterpret_cast<const uint4*>(h + (size_t)wd3.x * 128 + c0);
        a0 = fmaf(bflo(u0.x), w0, a0); a1 = fmaf(bfhi(u0.x), w0, a1);
        a2 = fmaf(bflo(u0.y), w0, a2); a3 = fmaf(bfhi(u0.y), w0, a3);
        a4 = fmaf(bflo(u0.z), w0, a4); a5 = fmaf(bfhi(u0.z), w0, a5);
        a6 = fmaf(bflo(u0.w), w0, a6); a7 = fmaf(bfhi(u0.w), w0, a7);
        a0 = fmaf(bflo(u1.x), w1, a0); a1 = fmaf(bfhi(u1.x), w1, a1);
        a2 = fmaf(bflo(u1.y), w1, a2); a3 = fmaf(bfhi(u1.y), w1, a3);
        a4 = fmaf(bflo(u1.z), w1, a4); a5 = fmaf(bfhi(u1.z), w1, a5);
        a6 = fmaf(bflo(u1.w), w1, a6); a7 = fmaf(bfhi(u1.w), w1, a7);
        a0 = fmaf(bflo(u2.x), w2, a0); a1 = fmaf(bfhi(u2.x), w2, a1);
        a2 = fmaf(bflo(u2.y), w2, a2); a3 = fmaf(bfhi(u2.y), w2, a3);
        a4 = fmaf(bflo(u2.z), w2, a4); a5 = fmaf(bfhi(u2.z), w2, a5);
        a6 = fmaf(bflo(u2.w), w2, a6); a7 = fmaf(bfhi(u2.w), w2, a7);
        a0 = fmaf(bflo(u3.x), w3, a0); a1 = fmaf(bfhi(u3.x), w3, a1);
        a2 = fmaf(bflo(u3.y), w3, a2); a3 = fmaf(bfhi(u3.y), w3, a3);
        a4 = fmaf(bflo(u3.z), w3, a4); a5 = fmaf(bfhi(u3.z), w3, a5);
        a6 = fmaf(bflo(u3.w), w3, a6); a7 = fmaf(bfhi(u3.w), w3, a7);
    }

    a0 += __shfl_xor(a0, 16); a0 += __shfl_xor(a0, 32);
    a1 += __shfl_xor(a1, 16); a1 += __shfl_xor(a1, 32);
    a2 += __shfl_xor(a2, 16); a2 += __shfl_xor(a2, 32);
    a3 += __shfl_xor(a3, 16); a3 += __shfl_xor(a3, 32);
    a4 += __shfl_xor(a4, 16); a4 += __shfl_xor(a4, 32);
    a5 += __shfl_xor(a5, 16); a5 += __shfl_xor(a5, 32);
    a6 += __shfl_xor(a6, 16); a6 += __shfl_xor(a6, 32);
    a7 += __shfl_xor(a7, 16); a7 += __shfl_xor(a7, 32);

    if (q == 0) {
        float dv = dinv[vtx];
        float dvv = dv * dv;
        uint4 us = *reinterpret_cast<const uint4*>(h + (size_t)vtx * 128 + c0);
        float4 A0 = *reinterpret_cast<const float4*>(fA + c0);
        float4 A1 = *reinterpret_cast<const float4*>(fA + c0 + 4);
        float4 C0 = *reinterpret_cast<const float4*>(fC + c0);
        float4 C1 = *reinterpret_cast<const float4*>(fC + c0 + 4);
        float v0 = fmaf(a0, dv * A0.x, fmaf(bflo(us.x), dvv * A0.x, C0.x));
        float v1 = fmaf(a1, dv * A0.y, fmaf(bfhi(us.x), dvv * A0.y, C0.y));
        float v2 = fmaf(a2, dv * A0.z, fmaf(bflo(us.y), dvv * A0.z, C0.z));
        float v3 = fmaf(a3, dv * A0.w, fmaf(bfhi(us.y), dvv * A0.w, C0.w));
        float v4 = fmaf(a4, dv * A1.x, fmaf(bflo(us.z), dvv * A1.x, C1.x));
        float v5 = fmaf(a5, dv * A1.y, fmaf(bfhi(us.z), dvv * A1.y, C1.y));
        float v6 = fmaf(a6, dv * A1.z, fmaf(bflo(us.w), dvv * A1.z, C1.z));
        float v7 = fmaf(a7, dv * A1.w, fmaf(bfhi(us.w), dvv * A1.w, C1.w));
        v0 = fmaxf(v0, 0.f); v1 = fmaxf(v1, 0.f); v2 = fmaxf(v2, 0.f); v3 = fmaxf(v3, 0.f);
        v4 = fmaxf(v4, 0.f); v5 = fmaxf(v5, 0.f); v6 = fmaxf(v6, 0.f); v7 = fmaxf(v7, 0.f);
        uint4 packed;
        packed.x = (unsigned)f2bf(v0) | ((unsigned)f2bf(v1) << 16);
        packed.y = (unsigned)f2bf(v2) | ((unsigned)f2bf(v3) << 16);
        packed.z = (unsigned)f2bf(v4) | ((unsigned)f2bf(v5) << 16);
        packed.w = (unsigned)f2bf(v6) | ((unsigned)f2bf(v7) << 16);
        *reinterpret_cast<uint4*>(out + (size_t)vtx * 128 + c0) = packed;
    }
}

// ---------------- pooling + classifier fused: one block (4 waves) per graph -------
__global__ __launch_bounds__(256) void k_poolfinal(const ushort* __restrict__ h,
                                                   const int* __restrict__ batch,
                                                   const float* __restrict__ lw,
                                                   const float* __restrict__ lb,
                                                   float* __restrict__ out, int n) {
    __shared__ float psum[4][128];
    __shared__ float pool[128];
    int g = blockIdx.x;
    int tid = threadIdx.x;
    int wave = tid >> 6, lane = tid & 63;
    int lo = 0, hi = n;
    while (lo < hi) { int m = (lo + hi) >> 1; if (batch[m] < g) lo = m + 1; else hi = m; }
    int a = lo;
    lo = 0; hi = n;
    int g1 = g + 1;
    while (lo < hi) { int m = (lo + hi) >> 1; if (batch[m] < g1) lo = m + 1; else hi = m; }
    int b = lo;

    int c0 = lane * 2;
    float a0 = 0.f, a1 = 0.f;
    int i = a + wave;
    for (; i + 12 < b; i += 16) {
        unsigned u0 = *reinterpret_cast<const unsigned*>(h + (size_t)i * 128 + c0);
        unsigned u1 = *reinterpret_cast<const unsigned*>(h + (size_t)(i + 4) * 128 + c0);
        unsigned u2 = *reinterpret_cast<const unsigned*>(h + (size_t)(i + 8) * 128 + c0);
        unsigned u3 = *reinterpret_cast<const unsigned*>(h + (size_t)(i + 12) * 128 + c0);
        a0 += bflo(u0) + bflo(u1) + bflo(u2) + bflo(u3);
        a1 += bfhi(u0) + bfhi(u1) + bfhi(u2) + bfhi(u3);
    }
    for (; i < b; i += 4) {
        unsigned u = *reinterpret_cast<const unsigned*>(h + (size_t)i * 128 + c0);
        a0 += bflo(u); a1 += bfhi(u);
    }
    psum[wave][c0] = a0;
    psum[wave][c0 + 1] = a1;
    __syncthreads();
    if (tid < 128) pool[tid] = psum[0][tid] + psum[1][tid] + psum[2][tid] + psum[3][tid];
    __syncthreads();
    if (tid < N_CLASSES) {
        float inv = 1.0f / fmaxf((float)(b - a), 1.0f);
        float s = 0.f;
        for (int k = 0; k < 128; ++k) s = fmaf(pool[k], lw[k * N_CLASSES + tid], s);
        out[g * N_CLASSES + tid] = s * inv + lb[tid];
    }
}

// ---------------- launch ----------------
extern "C" void kernel_launch(void* const* d_in, const int* in_sizes, int n_in,
                              void* d_out, int out_size, void* d_ws, size_t ws_size,
                              hipStream_t stream) {
    const float* x      = (const float*)d_in[0];
    const int*   ei     = (const int*)d_in[1];
    const int*   batch  = (const int*)d_in[2];
    const float* W0  = (const float*)d_in[3];
    const float* b0  = (const float*)d_in[4];
    const float* g0  = (const float*)d_in[5];
    const float* bt0 = (const float*)d_in[6];
    const float* m0  = (const float*)d_in[7];
    const float* v0  = (const float*)d_in[8];
    const float* W1  = (const float*)d_in[9];
    const float* b1  = (const float*)d_in[10];
    const float* g1  = (const float*)d_in[11];
    const float* bt1 = (const float*)d_in[12];
    const float* m1  = (const float*)d_in[13];
    const float* v1  = (const float*)d_in[14];
    const float* W2  = (const float*)d_in[15];
    const float* b2  = (const float*)d_in[16];
    const float* g2  = (const float*)d_in[17];
    const float* bt2 = (const float*)d_in[18];
    const float* m2  = (const float*)d_in[19];
    const float* v2  = (const float*)d_in[20];
    const float* lw  = (const float*)d_in[21];
    const float* lb  = (const float*)d_in[22];
    float* out = (float*)d_out;

    const int N = in_sizes[2];          // 50000
    const int E = in_sizes[1] / 2;      // 800000
    const int* row = ei;
    const int* col = ei + E;

    char* ws = (char*)d_ws;
    size_t off = 0;
    auto alloc = [&](size_t bytes) {
        void* p = ws + off;
        off += (bytes + 511) & ~(size_t)511;
        return p;
    };
    ushort* hA     = (ushort*)alloc((size_t)N * 128 * 2);   // bf16 activations
    ushort* hB     = (ushort*)alloc((size_t)N * 128 * 2);
    ushort* Wt0    = (ushort*)alloc((size_t)128 * IN_C * 2);
    ushort* Wt1    = (ushort*)alloc((size_t)128 * HID_C * 2);
    ushort* Wt2    = (ushort*)alloc((size_t)128 * HID_C * 2);
    int*   ecnt    = (int*)alloc((size_t)N * 4);
    int*   rank    = (int*)alloc((size_t)E * 4);
    int*   row_ptr = (int*)alloc((size_t)(N + 1) * 4);
    int2*  wedge   = (int2*)alloc((size_t)E * 8);
    float* dinv    = (float*)alloc((size_t)N * 4);
    int*   bsum    = (int*)alloc(256 * 4);
    float* fA      = (float*)alloc(3 * 128 * 4);
    float* fC      = (float*)alloc(3 * 128 * 4);

    const int NB_n  = (N + 255) / 256;        // 196
    const int NB_e4 = (E / 4 + 255) / 256;    // 782
    const int GB    = (N + 63) / 64;          // 782
    const int AB    = (N + 3) / 4;            // 12500

    // edges per fused-gemm0 block: jiters batches of 256
    const int epb    = (E + GB - 1) / GB;           // 1023
    const int jiters = (epb + 255) / 256;           // 4

    const int PW = (128 * (IN_C + 2 * HID_C) + 3 * 128 + 255) / 256;  // covers N too
    k_prepWF<<<PW, 256, 0, stream>>>(W0, W1, W2, Wt0, Wt1, Wt2,
                                     b0, g0, bt0, m0, v0,
                                     b1, g1, bt1, m1, v1,
                                     b2, g2, bt2, m2, v2, fA, fC, ecnt, N);

    // fused: gemm0 (waves 0-3) + count_rank (wave 4)
    k_gemm0_count<<<GB, 320, IN_C * 128 * 2, stream>>>(x, Wt0, hB, N,
                                                       col, ecnt, rank, E, jiters);
    k_scanA<<<NB_n, 256, 0, stream>>>(ecnt, row_ptr, bsum, dinv, N);
    k_scanC<<<NB_n, 256, 0, stream>>>(ecnt, row_ptr, bsum, NB_n, N, E);
    k_fill<<<NB_e4, 256, 0, stream>>>(row, col, row_ptr, rank, dinv, wedge, E);

    // layer 0 aggregate
    k_aggbf<<<AB, 256, 0, stream>>>(hB, row_ptr, wedge, dinv, fA, fC, hA, N);
    // layer 1
    k_gemmbf<HID_C><<<GB, 256, HID_C * 128 * 2, stream>>>(hA, Wt1, hB, N);
    k_aggbf<<<AB, 256, 0, stream>>>(hB, row_ptr, wedge, dinv, fA + 128, fC + 128, hA, N);
    // layer 2
    k_gemmbf<HID_C><<<GB, 256, HID_C * 128 * 2, stream>>>(hA, Wt2, hB, N);
    k_aggbf<<<AB, 256, 0, stream>>>(hB, row_ptr, wedge, dinv, fA + 256, fC + 256, hA, N);

    // pooling + classifier (one block per graph; batch is sorted)
    k_poolfinal<<<N_GRAPHS, 256, 0, stream>>>(hA, batch, lw, lb, out, N);
}